// Round 2
// baseline (204.876 us; speedup 1.0000x reference)
//
#include <hip/hip_runtime.h>
#include <hip/hip_bf16.h>
#include <math.h>

#define LSEQ 32768
#define DMODEL 256
#define DHID 256
#define NCH 512                 // interleaved [re,im] hidden channels
#define CHUNK 64
#define NCHUNKS (LSEQ / CHUNK)  // 512

typedef __bf16 bf16_t;
typedef __bf16 bf16x8 __attribute__((ext_vector_type(8)));
typedef __bf16 bf16x2 __attribute__((ext_vector_type(2)));
typedef float f32x4 __attribute__((ext_vector_type(4)));

// ---------------- prep: lambda and lambda^CHUNK (fp64 for phase accuracy) ----
// lam[2h],lam[2h+1] = Re/Im(lambda_h); lam[512+2h..] = Re/Im(lambda_h^CHUNK)
__global__ void prep_params(const float* __restrict__ nu_log,
                            const float* __restrict__ theta_log,
                            float* __restrict__ lam) {
  int h = threadIdx.x;
  double nu = exp((double)nu_log[h]);
  double th = exp((double)theta_log[h]);
  double mag = exp(-nu);
  lam[2 * h]     = (float)(mag * cos(th));
  lam[2 * h + 1] = (float)(mag * sin(th));
  double magC = exp(-(double)CHUNK * nu);
  double phC  = fmod((double)CHUNK * th, 6.283185307179586);
  lam[2 * DHID + 2 * h]     = (float)(magC * cos(phC));
  lam[2 * DHID + 2 * h + 1] = (float)(magC * sin(phC));
}

// W1 rows interleaved: row 2h = B_re[h]*gamma, row 2h+1 = B_im[h]*gamma
__global__ void pack_w1(const float* __restrict__ B_re, const float* __restrict__ B_im,
                        const float* __restrict__ gamma_log, bf16_t* __restrict__ W1) {
  int n = blockIdx.x, k = threadIdx.x;
  int h = n >> 1;
  float g = expf(gamma_log[h]);
  float v = ((n & 1) ? B_im[h * DMODEL + k] : B_re[h * DMODEL + k]) * g;
  W1[n * DMODEL + k] = (bf16_t)v;
}

// W2 cols interleaved to match Hb: W2[m][2h]=C_re[m][h], W2[m][2h+1]=-C_im[m][h]
__global__ void pack_w2(const float* __restrict__ C_re, const float* __restrict__ C_im,
                        bf16_t* __restrict__ W2) {
  int m = blockIdx.x, k = threadIdx.x;  // 512 threads
  int h = k >> 1;
  float v = (k & 1) ? -C_im[m * DHID + h] : C_re[m * DHID + h];
  W2[m * NCH + k] = (bf16_t)v;
}

// ---------------- LDS-free bf16 NT GEMM: C[L x N] = A[L x K] * Bw[N x K]^T ---
// 128x128 block tile, 4 waves 2x2, each wave 4x4 of 16x16x32 MFMA.
// Fragments loaded straight from global (B is L2-resident weights).
template <int K, int A_F32, int OUT_BF16, int FUSE>
__global__ __launch_bounds__(256) void gemm_bt(
    const void* __restrict__ Av, const bf16_t* __restrict__ Bw,
    void* __restrict__ Cv, int N,
    const float* __restrict__ X, const float* __restrict__ Dv) {
  const int tid = threadIdx.x;
  const int wave = tid >> 6, lane = tid & 63;
  const int wm = wave & 1, wn = wave >> 1;
  const int lrow = lane & 15, lk = lane >> 4;
  const int r0 = blockIdx.y * 128 + wm * 64;
  const int c0 = blockIdx.x * 128 + wn * 64;

  f32x4 acc[4][4] = {};
  const bf16_t* Ab = (const bf16_t*)Av;
  const float* Af = (const float*)Av;

#pragma unroll 2
  for (int k0 = 0; k0 < K; k0 += 32) {
    const int kk = k0 + lk * 8;
    bf16x8 af[4], bfr[4];
#pragma unroll
    for (int i = 0; i < 4; ++i) {
      int row = r0 + i * 16 + lrow;
      if (A_F32) {
        float4 u0 = *(const float4*)(Af + (size_t)row * K + kk);
        float4 u1 = *(const float4*)(Af + (size_t)row * K + kk + 4);
        bf16x8 t = {(bf16_t)u0.x, (bf16_t)u0.y, (bf16_t)u0.z, (bf16_t)u0.w,
                    (bf16_t)u1.x, (bf16_t)u1.y, (bf16_t)u1.z, (bf16_t)u1.w};
        af[i] = t;
      } else {
        af[i] = *(const bf16x8*)(Ab + (size_t)row * K + kk);
      }
    }
#pragma unroll
    for (int j = 0; j < 4; ++j)
      bfr[j] = *(const bf16x8*)(Bw + (size_t)(c0 + j * 16 + lrow) * K + kk);
#pragma unroll
    for (int i = 0; i < 4; ++i)
#pragma unroll
      for (int j = 0; j < 4; ++j)
        acc[i][j] = __builtin_amdgcn_mfma_f32_16x16x32_bf16(af[i], bfr[j], acc[i][j], 0, 0, 0);
  }

#pragma unroll
  for (int i = 0; i < 4; ++i) {
#pragma unroll
    for (int r = 0; r < 4; ++r) {
      int row = r0 + i * 16 + lk * 4 + r;
#pragma unroll
      for (int j = 0; j < 4; ++j) {
        int col = c0 + j * 16 + lrow;
        float v = acc[i][j][r];
        if (FUSE) v += X[(size_t)row * DMODEL + col] * Dv[col];
        if (OUT_BF16) ((bf16_t*)Cv)[(size_t)row * N + col] = (bf16_t)v;
        else          ((float*)Cv)[(size_t)row * N + col] = v;
      }
    }
  }
}

// ---------------- scan pass 1: per-chunk local end state ---------------------
// Bu is bf16 interleaved: uint at [t*256 + h] = (re_h | im_h<<16)
__global__ void scan_pass1(const unsigned int* __restrict__ Bu,
                           const float* __restrict__ lam, float2* __restrict__ E) {
  int c = blockIdx.x, h = threadIdx.x;
  float lre = lam[2 * h], lim = lam[2 * h + 1];
  float sre = 0.f, sim = 0.f;
  const unsigned int* p = Bu + (size_t)c * CHUNK * 256 + h;
#pragma unroll 8
  for (int t = 0; t < CHUNK; ++t) {
    unsigned int u = p[t * 256];
    float bre = __uint_as_float(u << 16);
    float bim = __uint_as_float(u & 0xffff0000u);
    float nre = fmaf(lre, sre, fmaf(-lim, sim, bre));
    float nim = fmaf(lre, sim, fmaf(lim, sre, bim));
    sre = nre; sim = nim;
  }
  E[(size_t)c * 256 + h] = make_float2(sre, sim);
}

// ---------------- scan pass 2: Kogge-Stone over chunks (block per channel) ---
__global__ void scan_pass2(const float2* __restrict__ E, const float* __restrict__ lam,
                           float2* __restrict__ Sc) {
  int h = blockIdx.x, c = threadIdx.x;  // c in [0, NCHUNKS)
  __shared__ float Ar[NCHUNKS], Ai[NCHUNKS], br[NCHUNKS], bi[NCHUNKS];
  float aR = lam[2 * DHID + 2 * h], aI = lam[2 * DHID + 2 * h + 1];
  float2 e = E[(size_t)c * 256 + h];
  float bR = e.x, bI = e.y;
  Ar[c] = aR; Ai[c] = aI; br[c] = bR; bi[c] = bI;
  __syncthreads();
  for (int off = 1; off < NCHUNKS; off <<= 1) {
    float paR = 0, paI = 0, pbR = 0, pbI = 0;
    bool has = (c >= off);
    if (has) { paR = Ar[c - off]; paI = Ai[c - off]; pbR = br[c - off]; pbI = bi[c - off]; }
    __syncthreads();
    if (has) {
      float nAR = aR * paR - aI * paI;
      float nAI = aR * paI + aI * paR;
      float nbR = aR * pbR - aI * pbI + bR;
      float nbI = aR * pbI + aI * pbR + bI;
      aR = nAR; aI = nAI; bR = nbR; bI = nbI;
      Ar[c] = aR; Ai[c] = aI; br[c] = bR; bi[c] = bI;
    }
    __syncthreads();
  }
  float inR = (c > 0) ? br[c - 1] : 0.f;
  float inI = (c > 0) ? bi[c - 1] : 0.f;
  Sc[(size_t)c * 256 + h] = make_float2(inR, inI);
}

// ---------------- scan pass 3: re-scan with carry, emit h bf16 interleaved ---
__global__ void scan_pass3(const unsigned int* __restrict__ Bu,
                           const float* __restrict__ lam,
                           const float2* __restrict__ Sc, bf16x2* __restrict__ Hb) {
  int c = blockIdx.x, h = threadIdx.x;
  float lre = lam[2 * h], lim = lam[2 * h + 1];
  float2 s0 = Sc[(size_t)c * 256 + h];
  float sre = s0.x, sim = s0.y;
  const unsigned int* p = Bu + (size_t)c * CHUNK * 256 + h;
  bf16x2* q = Hb + (size_t)c * CHUNK * 256 + h;
#pragma unroll 8
  for (int t = 0; t < CHUNK; ++t) {
    unsigned int u = p[t * 256];
    float bre = __uint_as_float(u << 16);
    float bim = __uint_as_float(u & 0xffff0000u);
    float nre = fmaf(lre, sre, fmaf(-lim, sim, bre));
    float nim = fmaf(lre, sim, fmaf(lim, sre, bim));
    sre = nre; sim = nim;
    bf16x2 o = {(bf16_t)sre, (bf16_t)sim};
    q[t * 256] = o;
  }
}

extern "C" void kernel_launch(void* const* d_in, const int* in_sizes, int n_in,
                              void* d_out, int out_size, void* d_ws, size_t ws_size,
                              hipStream_t stream) {
  const float* inputs    = (const float*)d_in[0];
  const float* nu_log    = (const float*)d_in[1];
  const float* theta_log = (const float*)d_in[2];
  const float* gamma_log = (const float*)d_in[3];
  const float* B_re      = (const float*)d_in[4];
  const float* B_im      = (const float*)d_in[5];
  const float* C_re      = (const float*)d_in[6];
  const float* C_im      = (const float*)d_in[7];
  const float* Dvec      = (const float*)d_in[8];
  float* out = (float*)d_out;

  char* w = (char*)d_ws;
  bf16_t* W1 = (bf16_t*)w;  w += (size_t)NCH * DMODEL * 2;    // 256 KB
  bf16_t* W2 = (bf16_t*)w;  w += (size_t)DMODEL * NCH * 2;    // 256 KB
  float* lam = (float*)w;   w += (size_t)4 * DHID * 4;        // 4 KB
  bf16_t* Bu = (bf16_t*)w;  w += (size_t)LSEQ * NCH * 2;      // 32 MB (bf16 interleaved)
  float2* E  = (float2*)w;  w += (size_t)NCHUNKS * DHID * 8;  // 1 MB
  float2* Sc = (float2*)w;  w += (size_t)NCHUNKS * DHID * 8;  // 1 MB
  bf16x2* Hb = (bf16x2*)w;  w += (size_t)LSEQ * NCH * 2;      // 32 MB

  prep_params<<<1, 256, 0, stream>>>(nu_log, theta_log, lam);
  pack_w1<<<NCH, DMODEL, 0, stream>>>(B_re, B_im, gamma_log, W1);
  pack_w2<<<DMODEL, NCH, 0, stream>>>(C_re, C_im, W2);

  // GEMM1: Bu[L x 512](bf16) = inputs[L x 256](f32->bf16) @ W1[512 x 256]^T
  gemm_bt<DMODEL, 1, 1, 0><<<dim3(NCH / 128, LSEQ / 128), 256, 0, stream>>>(
      inputs, W1, (void*)Bu, NCH, nullptr, nullptr);

  scan_pass1<<<NCHUNKS, 256, 0, stream>>>((const unsigned int*)Bu, lam, E);
  scan_pass2<<<DHID, NCHUNKS, 0, stream>>>(E, lam, Sc);
  scan_pass3<<<NCHUNKS, 256, 0, stream>>>((const unsigned int*)Bu, lam, Sc, Hb);

  // GEMM2: out[L x 256](f32) = Hb[L x 512](bf16) @ W2[256 x 512]^T + inputs*D
  gemm_bt<NCH, 0, 0, 1><<<dim3(DMODEL / 128, LSEQ / 128), 256, 0, stream>>>(
      (const void*)Hb, W2, (void*)out, DMODEL, inputs, Dvec);
}